// Round 8
// baseline (3318.984 us; speedup 1.0000x reference)
//
#include <hip/hip_runtime.h>
#include <math.h>

#define Bb 64
#define Ll 512
#define Dd 512
#define Ff 2048
#define Ee 8

typedef _Float16 half_t;
typedef _Float16 half8 __attribute__((ext_vector_type(8)));
typedef float f32x4 __attribute__((ext_vector_type(4)));

// ws layout (halves): W1t [E][F][D] at 0 ; W2t [E][D][F] at W2T_OFF
#define W2T_OFF ((size_t)Ee * Dd * Ff)

__device__ __forceinline__ void dma16(const half_t* g, half_t* l) {
    // global -> LDS direct DMA, 16B per lane; LDS dst = uniform base + lane*16
    __builtin_amdgcn_global_load_lds((const __attribute__((address_space(1))) void*)g,
                                     (__attribute__((address_space(3))) void*)l, 16, 0, 0);
}

// ---------------- prep: fp32 [R][C] -> fp16 [C][R] transpose ----------------
__global__ __launch_bounds__(256)
void prep_transpose(const float* __restrict__ w1, const float* __restrict__ w2,
                    half_t* __restrict__ ws)
{
    __shared__ half_t T[64 * 72];
    int bid = blockIdx.x;
    const float* src; half_t* dst; int R, C, r0, c0;
    if (bid < 2048) {            // W1 per e: R=512(d), C=2048(f): 8 x 32 tiles
        int e = bid >> 8, t = bid & 255;
        r0 = (t >> 5) * 64; c0 = (t & 31) * 64;
        src = w1 + (size_t)e * Dd * Ff;
        dst = ws + (size_t)e * Ff * Dd;
        R = Dd; C = Ff;
    } else {                     // W2 per e: R=2048(f), C=512(d): 32 x 8 tiles
        bid -= 2048;
        int e = bid >> 8, t = bid & 255;
        r0 = (t >> 3) * 64; c0 = (t & 7) * 64;
        src = w2 + (size_t)e * Ff * Dd;
        dst = ws + W2T_OFF + (size_t)e * Dd * Ff;
        R = Ff; C = Dd;
    }
    const int cx = threadIdx.x & 63, ry = threadIdx.x >> 6;
    #pragma unroll
    for (int j = 0; j < 16; ++j) {
        int r = ry * 16 + j;
        T[cx * 72 + r] = (half_t)src[(size_t)(r0 + r) * C + c0 + cx];
    }
    __syncthreads();
    const int rx = threadIdx.x & 7;
    #pragma unroll
    for (int it = 0; it < 2; ++it) {
        int cr = (threadIdx.x >> 3) + it * 32;
        *(half8*)&dst[(size_t)(c0 + cr) * R + r0 + rx * 8] = *(half8*)&T[cr * 72 + rx * 8];
    }
}

// ---------------- main fused MoE ----------------
// Block = (b, 64-token tile), 256 thr / 4 waves, LDS 64KB, regs<=256
// -> TWO blocks/CU with INDEPENDENT barrier domains (the m114 overlap: while
// block A drains vmcnt(0) at __syncthreads, block B's waves feed MFMA/LDS).
// Weight traffic per block identical to r1 (4MB/expert) - no r3 explosion.
// Wave owns 16 tokens x full 128-wide tile: 32 MFMA + 32 ds_read per step;
// Phase-A->B handoff is wave-private (4KB transpose scratch overlaid on the
// dead W-buffer at kc3 - no cross-wave Hs). Swizzles/fragments = r1 verbatim.
__global__ __launch_bounds__(256, 2)
void moe_main(const float* __restrict__ x, const float* __restrict__ logits,
              const int* __restrict__ masks, const half_t* __restrict__ ws,
              const float* __restrict__ b1, const float* __restrict__ b2,
              float* __restrict__ out)
{
    __shared__ half_t Wbuf[2][128 * 128];   // 2 x 32KB ping-pong; Wbuf[0] doubles
                                            // as per-wave H scratch at kc3
    const int tid  = threadIdx.x;
    const int wv   = tid >> 6;    // 0..3 = 16-token tile
    const int lane = tid & 63;
    const int nl   = lane & 15;
    const int q    = lane >> 4;
    const int rl   = lane >> 4;   // DMA row-within-4
    const int pcl  = lane & 15;   // DMA 16B slot

    const int bid = blockIdx.x;
    const int rk  = bid >> 3;            // LPT rank (heavy rows first)
    const int l0  = (bid & 7) * 64;      // tiles of one b spread across XCDs

    // ---- LPT rank -> b: rk-th heaviest batch row ----
    int b;
    {
        int cj = 0;
        #pragma unroll
        for (int e2 = 0; e2 < Ee; ++e2) cj += (masks[lane * Ee + e2] == 1);
        int rj = 0;
        for (int k = 0; k < Bb; ++k) {
            const int ck = __shfl(cj, k);
            rj += (ck > cj) || (ck == cj && k < lane);
        }
        const unsigned long long mword = __ballot(rj == rk);
        b = (int)__builtin_ctzll(mword);
    }

    // ---- gates: uniform softmax math; lane holds gate[lane&7] ----
    float mx = -1e30f;
    #pragma unroll
    for (int e = 0; e < Ee; ++e) mx = fmaxf(mx, logits[b * Ee + e]);
    float s = 0.f, gs = 0.f;
    unsigned am = 0u;
    #pragma unroll
    for (int e = 0; e < Ee; ++e) {
        const float ex = expf(logits[b * Ee + e] - mx);
        s += ex;
        if (masks[b * Ee + e] == 1) { gs += ex; am |= (1u << e); }
    }
    const int el = lane & 7;
    const float myg = ((am >> el) & 1u)
        ? expf(logits[b * Ee + el] - mx) / (gs + 1e-9f * s) : 0.f;

    // ---- persistent X A-fragments: wave's 16 tokens, 16 ksteps over K=512 ----
    half8 afrag[16];
    {
        const float* xrow = x + (size_t)(b * Ll + l0 + wv * 16 + nl) * Dd;
        #pragma unroll
        for (int ks = 0; ks < 16; ++ks) {
            const int c0 = ks * 32 + q * 8;
            const f32x4 u0 = *(const f32x4*)(xrow + c0);
            const f32x4 u1 = *(const f32x4*)(xrow + c0 + 4);
            half8 a;
            a[0]=(half_t)u0[0]; a[1]=(half_t)u0[1]; a[2]=(half_t)u0[2]; a[3]=(half_t)u0[3];
            a[4]=(half_t)u1[0]; a[5]=(half_t)u1[1]; a[6]=(half_t)u1[2]; a[7]=(half_t)u1[3];
            afrag[ks] = a;
        }
    }

    f32x4 oacc[32];   // [nc*8 + nt]: 16 tokens x 512 d per wave
    #pragma unroll
    for (int i = 0; i < 32; ++i) oacc[i] = (f32x4){0.f, 0.f, 0.f, 0.f};

    // 4 waves cover the 128-row tile: 32 rows / wave, 8 dma16 each
    auto stageT = [&](const half_t* src, int ld, half_t* dst) {
        #pragma unroll
        for (int ss = 0; ss < 8; ++ss) {
            const int row = wv * 32 + ss * 4 + rl;
            const int c = pcl ^ (row & 15);
            dma16(src + (size_t)row * ld + c * 8, dst + (wv * 32 + ss * 4) * 128);
        }
    };
    // Phase A: wave's 16 tokens x all 128 f-rows of the staged W1 tile
    auto computeA = [&](const half8* af, const half_t* Wb, f32x4* hc) {
        #pragma unroll
        for (int ks = 0; ks < 4; ++ks) {
            const half8 a = af[ks];
            #pragma unroll
            for (int nf = 0; nf < 8; ++nf) {
                const int row = nf * 16 + nl;
                const half8 bf = *(const half8*)&Wb[row * 128 + (((ks * 4 + q) ^ nl) * 8)];
                hc[nf] = __builtin_amdgcn_mfma_f32_16x16x32_f16(a, bf, hc[nf], 0, 0, 0);
            }
        }
    };
    // Phase B: wave's 16 tokens x all 128 d-rows of the staged W2 tile
    auto computeB = [&](const half8* ha, const half_t* Wb, f32x4* oc) {
        #pragma unroll
        for (int ks = 0; ks < 4; ++ks) {
            #pragma unroll
            for (int nt = 0; nt < 8; ++nt) {
                const int lr = nt * 16 + nl;
                const half8 bf = *(const half8*)&Wb[lr * 128 + (((ks * 4 + q) ^ nl) * 8)];
                oc[nt] = __builtin_amdgcn_mfma_f32_16x16x32_f16(ha[ks], bf, oc[nt], 0, 0, 0);
            }
        }
    };

    unsigned rem = am;
    if (rem) {  // prologue: stage first kc0 -> buf0 (drained by first sync)
        const int e0 = (int)__builtin_ctz(rem);
        stageT(ws + (size_t)e0 * Ff * Dd, Dd, Wbuf[0]);
    }

    #pragma unroll 1
    while (rem) {
        const int e = (int)__builtin_ctz(rem); rem &= rem - 1u;
        const int en = rem ? (int)__builtin_ctz(rem) : -1;
        const float g = __shfl(myg, e);
        const half_t* W1te = ws + (size_t)e * Ff * Dd;            // [F][D]
        const half_t* W2te = ws + W2T_OFF + (size_t)e * Dd * Ff;  // [D][F]
        const float*  b1e  = b1 + (size_t)e * Ff;
        const half_t* W1nx = (en >= 0) ? ws + (size_t)en * Ff * Dd : W1te;

        #pragma unroll 1
        for (int fci = 0; fci < 16; ++fci) {
            const int f0 = fci * 128;
            const half_t* WA = W1te + (size_t)f0 * Dd;  // + kc*128 col offset
            const half_t* WB = W2te + f0;               // + nc*128*Ff row offset
            const bool hn = (fci < 15) || (en >= 0);
            const half_t* An = (fci < 15) ? (WA + (size_t)128 * Dd) : W1nx;

            f32x4 hacc[8];
            #pragma unroll
            for (int i = 0; i < 8; ++i) hacc[i] = (f32x4){0.f, 0.f, 0.f, 0.f};

            // ---------- Phase A: 4 K-chunks of 128, 2-buffer ping-pong ----------
            __syncthreads();                         // kc0 tile landed
            stageT(WA + 128, Dd, Wbuf[1]);           // kc1
            computeA(&afrag[0], Wbuf[0], hacc);
            __syncthreads();
            stageT(WA + 2 * 128, Dd, Wbuf[0]);       // kc2
            computeA(&afrag[4], Wbuf[1], hacc);
            __syncthreads();
            stageT(WA + 3 * 128, Dd, Wbuf[1]);       // kc3
            computeA(&afrag[8], Wbuf[0], hacc);
            __syncthreads();
            computeA(&afrag[12], Wbuf[1], hacc);     // buf0 dead -> H scratch

            // ---- epilogue A: bias + gelu + gate -> wave-private scratch ----
            half_t* Hw = &Wbuf[0][wv * 2048];        // 4KB per wave
            #pragma unroll
            for (int nf = 0; nf < 8; ++nf) {
                const int fl = nf * 16 + nl;
                const float bv = b1e[f0 + fl];
                #pragma unroll
                for (int r = 0; r < 4; ++r) {
                    const int m = q * 4 + r;         // local token 0..15
                    const float v  = hacc[nf][r] + bv;
                    const float gl = 0.5f * v * (1.f + erff(v * 0.70710678118654752f));
                    Hw[m * 128 + (((fl >> 3) ^ m) * 8) + (fl & 7)] = (half_t)(g * gl);
                }
            }
            // read back own Phase-B A-fragments (wave-private; lgkm auto-waited)
            half8 ha[4];
            #pragma unroll
            for (int ks = 0; ks < 4; ++ks)
                ha[ks] = *(const half8*)&Hw[nl * 128 + (((ks * 4 + q) ^ nl) * 8)];

            // ---------- Phase B: 4 n-chunks of 128 ----------
            __syncthreads();                         // all waves done with scratch
            stageT(WB,                    Ff, Wbuf[0]);   // nc0
            stageT(WB + (size_t)128 * Ff, Ff, Wbuf[1]);   // nc1
            __syncthreads();                         // drain both
            computeB(ha, Wbuf[0], &oacc[0]);
            __syncthreads();
            stageT(WB + (size_t)256 * Ff, Ff, Wbuf[0]);   // nc2
            computeB(ha, Wbuf[1], &oacc[8]);
            __syncthreads();
            stageT(WB + (size_t)384 * Ff, Ff, Wbuf[1]);   // nc3
            computeB(ha, Wbuf[0], &oacc[16]);
            __syncthreads();
            if (hn) stageT(An, Dd, Wbuf[0]);              // next fci/e kc0
            computeB(ha, Wbuf[1], &oacc[24]);
        }
    }

    // ---- epilogue: add sum_e gate[e]*b2[e,:] and store fp32 ----
    #pragma unroll
    for (int nc = 0; nc < 4; ++nc) {
        #pragma unroll
        for (int nt = 0; nt < 8; ++nt) {
            const int dcol = nc * 128 + nt * 16 + nl;
            float bb = 0.f;
            #pragma unroll
            for (int e = 0; e < Ee; ++e) bb += __shfl(myg, e) * b2[e * Dd + dcol];
            const f32x4 v = oacc[nc * 8 + nt];
            const size_t base = (size_t)(b * Ll + l0 + wv * 16 + q * 4) * Dd + dcol;
            out[base]          = v[0] + bb;
            out[base + Dd]     = v[1] + bb;
            out[base + 2 * Dd] = v[2] + bb;
            out[base + 3 * Dd] = v[3] + bb;
        }
    }
}

__global__ void moe_loss(const float* __restrict__ logits, const int* __restrict__ masks,
                         float* __restrict__ loss_out)
{
    const int b = threadIdx.x;   // 64 threads = 1 wave
    float lg[Ee];
    float mx = -1e30f;
    #pragma unroll
    for (int e = 0; e < Ee; ++e) { lg[e] = logits[b * Ee + e]; mx = fmaxf(mx, lg[e]); }
    float s = 0.f;
    #pragma unroll
    for (int e = 0; e < Ee; ++e) { float ex = expf(lg[e] - mx); s += ex; lg[e] = ex; }
    float rs = 0.f;
    #pragma unroll
    for (int e = 0; e < Ee; ++e) if (masks[b * Ee + e] == 1) rs += lg[e] / s;
    #pragma unroll
    for (int off = 32; off > 0; off >>= 1) rs += __shfl_down(rs, off);
    if (b == 0) {
        const float t = 1.f - rs / (float)Bb;
        loss_out[0] = t * t;
    }
}

extern "C" void kernel_launch(void* const* d_in, const int* in_sizes, int n_in,
                              void* d_out, int out_size, void* d_ws, size_t ws_size,
                              hipStream_t stream)
{
    const float* x      = (const float*)d_in[0];
    const float* logits = (const float*)d_in[1];
    const int*   masks  = (const int*)d_in[2];
    const float* w1     = (const float*)d_in[3];
    const float* b1     = (const float*)d_in[4];
    const float* w2     = (const float*)d_in[5];
    const float* b2     = (const float*)d_in[6];
    float* out = (float*)d_out;
    half_t* ws = (half_t*)d_ws;

    hipLaunchKernelGGL(prep_transpose, dim3(4096), dim3(256), 0, stream, w1, w2, ws);
    hipLaunchKernelGGL(moe_main, dim3(512), dim3(256), 0, stream,
                       x, logits, masks, ws, b1, b2, out);
    hipLaunchKernelGGL(moe_loss, dim3(1), dim3(64), 0, stream,
                       logits, masks, out + (size_t)Bb * Ll * Dd);
}